// Round 5
// baseline (26807.895 us; speedup 1.0000x reference)
//
#include <hip/hip_runtime.h>
#include <math.h>

// Problem constants (match reference)
#define Hn   2560      // hidden units
#define Bn   64        // batch
#define INW  128       // input width
#define ETOT 2048      // total excitatory units (4 areas x 512)

__device__ __forceinline__ int area_of(int h) {
  return h < ETOT ? (h >> 9) : ((h - ETOT) >> 7);
}

// ---------------------------------------------------------------------------
// Prep 1: WT[k][h] = sign(k) * |Wrec[h][k]| * conn(h,k), diag removed.
// ---------------------------------------------------------------------------
__global__ void build_wrecT(const float* __restrict__ Wrec, float* __restrict__ WT) {
  __shared__ float tile[64][65];
  int h0 = blockIdx.x * 64;
  int k0 = blockIdx.y * 64;
  int tx = threadIdx.x;   // 0..63
  int ty = threadIdx.y;   // 0..15
  #pragma unroll
  for (int j = 0; j < 64; j += 16)
    tile[ty + j][tx] = Wrec[(size_t)(h0 + ty + j) * Hn + k0 + tx];
  __syncthreads();
  #pragma unroll
  for (int j = 0; j < 64; j += 16) {
    int k = k0 + ty + j;   // out row (source unit)
    int h = h0 + tx;       // out col (target unit), lane-minor -> coalesced
    float v = fabsf(tile[tx][ty + j]);
    int ah = area_of(h);
    int conn;
    float sgn;
    if (k < ETOT) { int ak = k >> 9; int d = ah - ak; conn = (d <= 1 && d >= -1); sgn = 1.f; }
    else          { int ak = (k - ETOT) >> 7; conn = (ah == ak); sgn = -1.f; }
    if (h == k) conn = 0;
    WT[(size_t)k * Hn + h] = conn ? sgn * v : 0.f;
  }
}

// ---------------------------------------------------------------------------
// Prep 2: WinT[i][h] = |Win[h][i]| * (area(h)==0). Row stride Hn (same as WT).
// ---------------------------------------------------------------------------
__global__ void build_winT(const float* __restrict__ Win, float* __restrict__ WinT) {
  __shared__ float tile[64][65];
  int h0 = blockIdx.x * 64;
  int i0 = blockIdx.y * 64;
  int tx = threadIdx.x, ty = threadIdx.y;
  #pragma unroll
  for (int j = 0; j < 64; j += 16)
    tile[ty + j][tx] = Win[(size_t)(h0 + ty + j) * INW + i0 + tx];
  __syncthreads();
  #pragma unroll
  for (int j = 0; j < 64; j += 16) {
    int i = i0 + ty + j;
    int h = h0 + tx;
    float v = fabsf(tile[tx][ty + j]);
    WinT[(size_t)i * Hn + h] = (area_of(h) == 0) ? v : 0.f;
  }
}

// ---------------------------------------------------------------------------
// Prep 3: inpT[t][i][b] = inputs[t][b][i].
// ---------------------------------------------------------------------------
__global__ void build_inpT(const float* __restrict__ inp, float* __restrict__ inpT) {
  __shared__ float tile[64 * 129];
  int t = blockIdx.x;
  const float* src = inp + (size_t)t * Bn * INW;
  float* dst = inpT + (size_t)t * INW * Bn;
  for (int idx = threadIdx.x; idx < Bn * INW; idx += blockDim.x) {
    int b = idx >> 7, i = idx & 127;
    tile[b * 129 + i] = src[idx];
  }
  __syncthreads();
  for (int idx = threadIdx.x; idx < Bn * INW; idx += blockDim.x) {
    int i = idx >> 6, b = idx & 63;
    dst[idx] = tile[b * 129 + i];
  }
}

// ---------------------------------------------------------------------------
// Fused per-step kernel: ONE dispatch per timestep, NO cross-block traffic.
// 160 blocks x 512 threads. Block = one 16-h group; its masked k-extent is
// cut into 32-k chunks dealt stride-8 to the block's 8 waves (<=8% imbalance).
// Wave tile: 16 h x 64 b x 32 k; lane = batch -> r coalesced, W wave-uniform.
// Split-k reduced IN LDS (32 KB), then bias + leaky-integrate + retanh +
// rdst/rates stores, all in-block. Cross-step visibility via kernel boundary.
// ---------------------------------------------------------------------------
__global__ __launch_bounds__(512) void rnn_step(
    const float* __restrict__ WT, const float* __restrict__ WinT,
    const float* __restrict__ inpT, const float* __restrict__ inp,
    const float* __restrict__ brec,
    const float* __restrict__ rsrc, float* __restrict__ rdst,
    float* __restrict__ xT, float* __restrict__ rates,
    int t, int useInpT)
{
  __shared__ float red[8][16][64];   // 32 KB split-k partials
  __shared__ float rrt[16][65];      // padded transpose tile for rates

  int hg   = blockIdx.x;             // 0..159
  int w    = threadIdx.x >> 6;       // wave id 0..7
  int lane = threadIdx.x & 63;       // = batch index
  int h0   = hg * 16;
  int a    = (hg < 128) ? (hg >> 5) : ((hg - 128) >> 3);
  int nE32 = (a == 0 || a == 3) ? 32 : 48;      // 32-k E chunks
  int kE0  = (a == 0 ? 0 : (a - 1)) * 512;
  int nch  = nE32 + 4 + (a == 0 ? 4 : 0);       // 40 / 52 / 52 / 36

  float acc[16];
  #pragma unroll
  for (int i = 0; i < 16; ++i) acc[i] = 0.f;

  for (int c = w; c < nch; c += 8) {
    const float* wp;      // 16 consecutive floats per k-row, row stride Hn
    const float* rp;      // [32][64] operand rows, stride 64
    bool rawInput = false;
    if (c < nE32) {
      int k0 = kE0 + (c << 5);
      wp = WT + (size_t)k0 * Hn + h0; rp = rsrc + ((size_t)k0 << 6);
    } else if (c < nE32 + 4) {
      int k0 = ETOT + (a << 7) + ((c - nE32) << 5);
      wp = WT + (size_t)k0 * Hn + h0; rp = rsrc + ((size_t)k0 << 6);
    } else {              // input-projection chunk (area 0 only)
      int i0 = (c - nE32 - 4) << 5;
      wp = WinT + (size_t)i0 * Hn + h0;
      if (useInpT) rp = inpT + (size_t)t * (INW * Bn) + ((size_t)i0 << 6);
      else { rp = inp + (size_t)t * (Bn * INW) + i0; rawInput = true; }
    }

    if (!rawInput) {
      #pragma unroll 4
      for (int k = 0; k < 32; ++k) {
        const float4* wq = (const float4*)(wp + (size_t)k * Hn);  // wave-uniform
        float4 w0 = wq[0], w1 = wq[1], w2 = wq[2], w3 = wq[3];
        float rv = rp[(k << 6) + lane];                           // coalesced
        acc[ 0] = fmaf(w0.x, rv, acc[ 0]);  acc[ 1] = fmaf(w0.y, rv, acc[ 1]);
        acc[ 2] = fmaf(w0.z, rv, acc[ 2]);  acc[ 3] = fmaf(w0.w, rv, acc[ 3]);
        acc[ 4] = fmaf(w1.x, rv, acc[ 4]);  acc[ 5] = fmaf(w1.y, rv, acc[ 5]);
        acc[ 6] = fmaf(w1.z, rv, acc[ 6]);  acc[ 7] = fmaf(w1.w, rv, acc[ 7]);
        acc[ 8] = fmaf(w2.x, rv, acc[ 8]);  acc[ 9] = fmaf(w2.y, rv, acc[ 9]);
        acc[10] = fmaf(w2.z, rv, acc[10]);  acc[11] = fmaf(w2.w, rv, acc[11]);
        acc[12] = fmaf(w3.x, rv, acc[12]);  acc[13] = fmaf(w3.y, rv, acc[13]);
        acc[14] = fmaf(w3.z, rv, acc[14]);  acc[15] = fmaf(w3.w, rv, acc[15]);
      }
    } else {
      #pragma unroll 4
      for (int k = 0; k < 32; ++k) {
        const float4* wq = (const float4*)(wp + (size_t)k * Hn);
        float4 w0 = wq[0], w1 = wq[1], w2 = wq[2], w3 = wq[3];
        float rv = rp[lane * INW + k];
        acc[ 0] = fmaf(w0.x, rv, acc[ 0]);  acc[ 1] = fmaf(w0.y, rv, acc[ 1]);
        acc[ 2] = fmaf(w0.z, rv, acc[ 2]);  acc[ 3] = fmaf(w0.w, rv, acc[ 3]);
        acc[ 4] = fmaf(w1.x, rv, acc[ 4]);  acc[ 5] = fmaf(w1.y, rv, acc[ 5]);
        acc[ 6] = fmaf(w1.z, rv, acc[ 6]);  acc[ 7] = fmaf(w1.w, rv, acc[ 7]);
        acc[ 8] = fmaf(w2.x, rv, acc[ 8]);  acc[ 9] = fmaf(w2.y, rv, acc[ 9]);
        acc[10] = fmaf(w2.z, rv, acc[10]);  acc[11] = fmaf(w2.w, rv, acc[11]);
        acc[12] = fmaf(w3.x, rv, acc[12]);  acc[13] = fmaf(w3.y, rv, acc[13]);
        acc[14] = fmaf(w3.z, rv, acc[14]);  acc[15] = fmaf(w3.w, rv, acc[15]);
      }
    }
  }

  #pragma unroll
  for (int h = 0; h < 16; ++h) red[w][h][lane] = acc[h];
  __syncthreads();

  // reduce + epilogue: 1024 (h,b) elements over 512 threads
  #pragma unroll
  for (int j = 0; j < 2; ++j) {
    int idx = threadIdx.x + j * 512;
    int h = idx >> 6, b = idx & 63;
    float sum = red[0][h][b];
    #pragma unroll
    for (int cc = 1; cc < 8; ++cc) sum += red[cc][h][b];
    float pre = sum + brec[h0 + h];
    size_t xi = (size_t)(h0 + h) * 64 + b;
    float x = xT[xi];
    x = 0.8f * x + 0.2f * pre;          // ALPHA_X = 0.2
    xT[xi] = x;
    float rr = tanhf(fmaxf(x, 0.f));
    rdst[xi] = rr;
    rrt[h][b] = rr;
  }
  __syncthreads();

  // rates[t][b][h0..h0+15]: h-minor across threads -> 64 B packed segments
  float* rt = rates + (size_t)t * (Bn * Hn) + h0;
  #pragma unroll
  for (int j = 0; j < 2; ++j) {
    int idx = threadIdx.x + j * 512;
    int b = idx >> 4, h = idx & 15;
    rt[(size_t)b * Hn + h] = rrt[h][b];
  }
}

// ---------------------------------------------------------------------------
extern "C" void kernel_launch(void* const* d_in, const int* in_sizes, int n_in,
                              void* d_out, int out_size, void* d_ws, size_t ws_size,
                              hipStream_t stream) {
  const float* inputs = (const float*)d_in[0];   // [T, 64, 128]
  const float* Wrec   = (const float*)d_in[1];   // [2560, 2560]
  const float* brec   = (const float*)d_in[2];   // [2560]
  const float* Win    = (const float*)d_in[3];   // [2560, 128]
  int T = in_sizes[0] / (Bn * INW);              // 500

  float* ws = (float*)d_ws;
  size_t off = 0;
  float* WT   = ws + off; off += (size_t)Hn * Hn;          // 26.2 MB
  float* WinT = ws + off; off += (size_t)INW * Hn;         // 1.3 MB
  float* xT   = ws + off; off += (size_t)Hn * Bn;
  float* rA   = ws + off; off += (size_t)Hn * Bn;
  float* rB   = ws + off; off += (size_t)Hn * Bn;
  float* inpT = ws + off;
  size_t needInpT = (off + (size_t)T * INW * Bn) * sizeof(float);
  int useInpT = (ws_size >= needInpT) ? 1 : 0;

  // x0 = 0, r0 = retanh(0) = 0  (ws poisoned 0xAA each call)
  hipMemsetAsync(xT, 0, (size_t)Hn * Bn * sizeof(float), stream);
  hipMemsetAsync(rA, 0, (size_t)Hn * Bn * sizeof(float), stream);

  build_wrecT<<<dim3(40, 40), dim3(64, 16), 0, stream>>>(Wrec, WT);
  build_winT<<<dim3(40, 2), dim3(64, 16), 0, stream>>>(Win, WinT);
  if (useInpT) build_inpT<<<T, 256, 0, stream>>>(inputs, inpT);

  float* rates = (float*)d_out;
  for (int t = 0; t < T; ++t) {
    const float* rs = (t & 1) ? rB : rA;
    float*       rd = (t & 1) ? rA : rB;
    rnn_step<<<160, 512, 0, stream>>>(WT, WinT, inpT, inputs, brec,
                                      rs, rd, xT, rates, t, useInpT);
  }
}

// Round 6
// 11381.154 us; speedup vs baseline: 2.3555x; 2.3555x over previous
//
#include <hip/hip_runtime.h>
#include <math.h>

// Problem constants (match reference)
#define Hn   2560      // hidden units
#define Bn   64        // batch
#define INW  128       // input width
#define ETOT 2048      // total excitatory units (4 areas x 512)
#define HGn  160       // h-groups of 16
#define MAXC 13        // max 128-k chunks per h-group

// ---------------------------------------------------------------------------
// Prep 1: packed masked weights.
// Wpack[g][c][k][16] : for h-group g (16 h outputs), chunk c (128 source rows),
// the signed masked weight sgn(k)*|Wrec[h][krow]| (diag zeroed), or |Win[h][i]|
// for the input chunk (area-0 groups only). Dense + sequential: the mm kernel
// streams it with coalesced vector loads (NO strided wave-uniform s_loads).
// grid (160, 13), block 256.
// ---------------------------------------------------------------------------
__global__ void build_wpack(const float* __restrict__ Wrec,
                            const float* __restrict__ Win,
                            float* __restrict__ Wpack) {
  __shared__ float tile[16][132];     // 16 h rows x 128 cols (+4 pad)
  int g = blockIdx.x, c = blockIdx.y;
  int a = (g < 128) ? (g >> 5) : ((g - 128) >> 3);
  int nE = (a == 0 || a == 3) ? 8 : 12;
  int nch = nE + 1 + (a == 0 ? 1 : 0);
  if (c >= nch) return;
  int h0 = g * 16;
  int tid = threadIdx.x;

  const float* src; int stride, k0; float sgn; bool isIn = false;
  if (c < nE)       { k0 = ((a == 0 ? 0 : a - 1) << 9) + (c << 7); src = Wrec; stride = Hn;  sgn =  1.f; }
  else if (c == nE) { k0 = ETOT + (a << 7);                        src = Wrec; stride = Hn;  sgn = -1.f; }
  else              { k0 = 0;                                      src = Win;  stride = INW; sgn =  1.f; isIn = true; }

  // read 16 rows x 128 cols, coalesced float4
  #pragma unroll
  for (int q = 0; q < 2; ++q) {
    int idx = tid + q * 256;          // float4 id, 512 total
    int row = idx >> 5, col4 = idx & 31;
    float4 v = ((const float4*)(src + (size_t)(h0 + row) * stride + k0))[col4];
    tile[row][col4 * 4 + 0] = v.x;
    tile[row][col4 * 4 + 1] = v.y;
    tile[row][col4 * 4 + 2] = v.z;
    tile[row][col4 * 4 + 3] = v.w;
  }
  __syncthreads();

  float* out = Wpack + ((size_t)(g * MAXC + c) << 11);   // 2048 floats/chunk
  #pragma unroll
  for (int q = 0; q < 8; ++q) {
    int idx = tid + q * 256;
    int k = idx >> 4, hh = idx & 15;
    float v = fabsf(tile[hh][k]);
    if (!isIn) { if (k0 + k == h0 + hh) v = 0.f; v *= sgn; }
    out[idx] = v;
  }
}

// ---------------------------------------------------------------------------
// Prep 2: inpT[t][i][b] = inputs[t][b][i].
// ---------------------------------------------------------------------------
__global__ void build_inpT(const float* __restrict__ inp, float* __restrict__ inpT) {
  __shared__ float tile[64 * 129];
  int t = blockIdx.x;
  const float* src = inp + (size_t)t * Bn * INW;
  float* dst = inpT + (size_t)t * INW * Bn;
  for (int idx = threadIdx.x; idx < Bn * INW; idx += blockDim.x) {
    int b = idx >> 7, i = idx & 127;
    tile[b * 129 + i] = src[idx];
  }
  __syncthreads();
  for (int idx = threadIdx.x; idx < Bn * INW; idx += blockDim.x) {
    int i = idx >> 6, b = idx & 63;
    dst[idx] = tile[b * 129 + i];
  }
}

// ---------------------------------------------------------------------------
// Kernel A (per step): masked GEMM partials. 1800 single-wave blocks
// (R3's best structure). W chunk (8 KB) staged to LDS with coalesced float4
// vector loads, then read per-k as 4 wave-uniform ds_read_b128 broadcasts —
// no strided scalar-path loads in the k-loop. The only global load per k is
// the sequential coalesced 256 B r-row.
// ---------------------------------------------------------------------------
__global__ __launch_bounds__(64) void rnn_mm(
    const float* __restrict__ Wpack,
    const float* __restrict__ inpT, const float* __restrict__ inp,
    const float* __restrict__ rsrc, float* __restrict__ part,
    int t, int useInpT)
{
  __shared__ float4 wlds[512];       // 8 KB: W chunk [128 k][16 h]
  int bid = blockIdx.x;
  int lane = threadIdx.x;

  // bid -> (h-group, chunk id)   [identical decode to R3]
  int hg, c;
  if (bid < 320)       { hg = bid / 10;                      c = bid - hg * 10;          }
  else if (bid < 1152) { int r = bid - 320;  hg = 32 + r / 13;  c = r - (hg - 32) * 13;  }
  else if (bid < 1440) { int r = bid - 1152; hg = 96 + r / 9;   c = r - (hg - 96) * 9;   }
  else if (bid < 1520) { int r = bid - 1440; hg = 128 + r / 10; c = r - (hg - 128) * 10; }
  else if (bid < 1728) { int r = bid - 1520; hg = 136 + r / 13; c = r - (hg - 136) * 13; }
  else                 { int r = bid - 1728; hg = 152 + r / 9;  c = r - (hg - 152) * 9;  }

  int a  = (hg < 128) ? (hg >> 5) : ((hg - 128) >> 3);
  int nE = (a == 0 || a == 3) ? 8 : 12;
  int kE0 = (a == 0 ? 0 : (a - 1)) * 512;

  const float* rp;          // [128][64] operand rows, stride 64
  bool rawInput = false;
  if (c < nE)       rp = rsrc + ((size_t)(kE0 + (c << 7)) << 6);
  else if (c == nE) rp = rsrc + ((size_t)(ETOT + (a << 7)) << 6);
  else {
    if (useInpT) rp = inpT + (size_t)t * (INW * Bn);
    else { rp = inp + (size_t)t * (Bn * INW); rawInput = true; }
  }

  // stage W chunk: 512 float4, coalesced (1 KB per instruction)
  const float4* wsrc = (const float4*)(Wpack + ((size_t)(hg * MAXC + c) << 11));
  #pragma unroll
  for (int q = 0; q < 8; ++q) wlds[lane + q * 64] = wsrc[lane + q * 64];
  __syncthreads();

  float acc[16];
  #pragma unroll
  for (int i = 0; i < 16; ++i) acc[i] = 0.f;

  if (!rawInput) {
    #pragma unroll 4
    for (int k = 0; k < 128; ++k) {
      float4 w0 = wlds[k * 4 + 0], w1 = wlds[k * 4 + 1];
      float4 w2 = wlds[k * 4 + 2], w3 = wlds[k * 4 + 3];   // LDS broadcast
      float rv = rp[(k << 6) + lane];                       // coalesced global
      acc[ 0] = fmaf(w0.x, rv, acc[ 0]);  acc[ 1] = fmaf(w0.y, rv, acc[ 1]);
      acc[ 2] = fmaf(w0.z, rv, acc[ 2]);  acc[ 3] = fmaf(w0.w, rv, acc[ 3]);
      acc[ 4] = fmaf(w1.x, rv, acc[ 4]);  acc[ 5] = fmaf(w1.y, rv, acc[ 5]);
      acc[ 6] = fmaf(w1.z, rv, acc[ 6]);  acc[ 7] = fmaf(w1.w, rv, acc[ 7]);
      acc[ 8] = fmaf(w2.x, rv, acc[ 8]);  acc[ 9] = fmaf(w2.y, rv, acc[ 9]);
      acc[10] = fmaf(w2.z, rv, acc[10]);  acc[11] = fmaf(w2.w, rv, acc[11]);
      acc[12] = fmaf(w3.x, rv, acc[12]);  acc[13] = fmaf(w3.y, rv, acc[13]);
      acc[14] = fmaf(w3.z, rv, acc[14]);  acc[15] = fmaf(w3.w, rv, acc[15]);
    }
  } else {
    #pragma unroll 4
    for (int k = 0; k < 128; ++k) {
      float4 w0 = wlds[k * 4 + 0], w1 = wlds[k * 4 + 1];
      float4 w2 = wlds[k * 4 + 2], w3 = wlds[k * 4 + 3];
      float rv = rp[lane * INW + k];
      acc[ 0] = fmaf(w0.x, rv, acc[ 0]);  acc[ 1] = fmaf(w0.y, rv, acc[ 1]);
      acc[ 2] = fmaf(w0.z, rv, acc[ 2]);  acc[ 3] = fmaf(w0.w, rv, acc[ 3]);
      acc[ 4] = fmaf(w1.x, rv, acc[ 4]);  acc[ 5] = fmaf(w1.y, rv, acc[ 5]);
      acc[ 6] = fmaf(w1.z, rv, acc[ 6]);  acc[ 7] = fmaf(w1.w, rv, acc[ 7]);
      acc[ 8] = fmaf(w2.x, rv, acc[ 8]);  acc[ 9] = fmaf(w2.y, rv, acc[ 9]);
      acc[10] = fmaf(w2.z, rv, acc[10]);  acc[11] = fmaf(w2.w, rv, acc[11]);
      acc[12] = fmaf(w3.x, rv, acc[12]);  acc[13] = fmaf(w3.y, rv, acc[13]);
      acc[14] = fmaf(w3.z, rv, acc[14]);  acc[15] = fmaf(w3.w, rv, acc[15]);
    }
  }

  // store partials (coalesced 256 B per h-row)
  float* pb = part + ((size_t)(hg * MAXC + c) * 16) * 64 + lane;
  #pragma unroll
  for (int h = 0; h < 16; ++h) pb[h * 64] = acc[h];
}

// ---------------------------------------------------------------------------
// Kernel B (per step): reduce partials + bias + leaky-integrate + retanh.
// 160 blocks x 256 threads; float4 everywhere; rates written as packed
// float4 segments via a padded LDS transpose tile.
// ---------------------------------------------------------------------------
__global__ __launch_bounds__(256) void rnn_fin(
    const float* __restrict__ part, const float* __restrict__ brec,
    float* __restrict__ xT, float* __restrict__ rdst,
    float* __restrict__ rates, int t)
{
  __shared__ float rrt[16][68];
  int hg = blockIdx.x;
  int a  = (hg < 128) ? (hg >> 5) : ((hg - 128) >> 3);
  int nE = (a == 0 || a == 3) ? 8 : 12;
  int nch = nE + 1 + (a == 0 ? 1 : 0);   // 10 / 13 / 13 / 9
  int h0 = hg * 16;
  int tid = threadIdx.x;
  int hh = tid >> 4, bq = tid & 15;      // (h, float4-of-b)

  const float4* p4 = (const float4*)part + (size_t)hg * MAXC * 256 + hh * 16 + bq;
  float4 s = make_float4(0.f, 0.f, 0.f, 0.f);
  for (int cc = 0; cc < nch; ++cc) {
    float4 v = p4[cc * 256];
    s.x += v.x; s.y += v.y; s.z += v.z; s.w += v.w;
  }
  float bb = brec[h0 + hh];
  float4* x4p = (float4*)xT + (size_t)(h0 + hh) * 16 + bq;
  float4 x = *x4p;
  x.x = 0.8f * x.x + 0.2f * (s.x + bb);   // ALPHA_X = 0.2
  x.y = 0.8f * x.y + 0.2f * (s.y + bb);
  x.z = 0.8f * x.z + 0.2f * (s.z + bb);
  x.w = 0.8f * x.w + 0.2f * (s.w + bb);
  *x4p = x;
  float4 r;
  r.x = tanhf(fmaxf(x.x, 0.f));
  r.y = tanhf(fmaxf(x.y, 0.f));
  r.z = tanhf(fmaxf(x.z, 0.f));
  r.w = tanhf(fmaxf(x.w, 0.f));
  ((float4*)rdst)[(size_t)(h0 + hh) * 16 + bq] = r;
  rrt[hh][bq * 4 + 0] = r.x;
  rrt[hh][bq * 4 + 1] = r.y;
  rrt[hh][bq * 4 + 2] = r.z;
  rrt[hh][bq * 4 + 3] = r.w;
  __syncthreads();

  // rates[t][b][h0..h0+15]: thread -> (b, h-quad), 64 B packed segments
  int b = tid >> 2, hq = tid & 3;
  float4 o = make_float4(rrt[hq * 4 + 0][b], rrt[hq * 4 + 1][b],
                         rrt[hq * 4 + 2][b], rrt[hq * 4 + 3][b]);
  *(float4*)(rates + (size_t)t * (Bn * Hn) + (size_t)b * Hn + h0 + hq * 4) = o;
}

// ---------------------------------------------------------------------------
extern "C" void kernel_launch(void* const* d_in, const int* in_sizes, int n_in,
                              void* d_out, int out_size, void* d_ws, size_t ws_size,
                              hipStream_t stream) {
  const float* inputs = (const float*)d_in[0];   // [T, 64, 128]
  const float* Wrec   = (const float*)d_in[1];   // [2560, 2560]
  const float* brec   = (const float*)d_in[2];   // [2560]
  const float* Win    = (const float*)d_in[3];   // [2560, 128]
  int T = in_sizes[0] / (Bn * INW);              // 500

  float* ws = (float*)d_ws;
  size_t off = 0;
  float* Wpack = ws + off; off += (size_t)HGn * MAXC * 2048;    // 17.0 MB
  float* xT    = ws + off; off += (size_t)Hn * Bn;
  float* rA    = ws + off; off += (size_t)Hn * Bn;
  float* rB    = ws + off; off += (size_t)Hn * Bn;
  float* part  = ws + off; off += (size_t)HGn * MAXC * 16 * 64; // 8.5 MB
  float* inpT  = ws + off;
  size_t needInpT = (off + (size_t)T * INW * Bn) * sizeof(float);
  int useInpT = (ws_size >= needInpT) ? 1 : 0;

  // x0 = 0, r0 = retanh(0) = 0  (ws poisoned 0xAA each call)
  hipMemsetAsync(xT, 0, (size_t)Hn * Bn * sizeof(float), stream);
  hipMemsetAsync(rA, 0, (size_t)Hn * Bn * sizeof(float), stream);

  build_wpack<<<dim3(HGn, MAXC), 256, 0, stream>>>(Wrec, Win, Wpack);
  if (useInpT) build_inpT<<<T, 256, 0, stream>>>(inputs, inpT);

  float* rates = (float*)d_out;
  for (int t = 0; t < T; ++t) {
    const float* rs = (t & 1) ? rB : rA;
    float*       rd = (t & 1) ? rA : rB;
    rnn_mm<<<1800, 64, 0, stream>>>(Wpack, inpT, inputs, rs, part, t, useInpT);
    rnn_fin<<<160, 256, 0, stream>>>(part, brec, xT, rd, rates, t);
  }
}

// Round 7
// 7481.837 us; speedup vs baseline: 3.5831x; 1.5212x over previous
//
#include <hip/hip_runtime.h>
#include <math.h>

// Problem constants (match reference)
#define Hn   2560      // hidden units
#define Bn   64        // batch
#define INW  128       // input width
#define ETOT 2048      // total excitatory units (4 areas x 512)
#define HGn  160       // h-groups of 16
#define MAXC 13        // max 128-k chunks per h-group

typedef __attribute__((ext_vector_type(8))) short short8;   // 8 bf16 = 4 VGPRs
typedef __attribute__((ext_vector_type(4))) float floatx4;  // MFMA acc

__device__ __forceinline__ unsigned short f2bf(float x) {   // RNE
  unsigned u = __float_as_uint(x);
  u += 0x7FFF + ((u >> 16) & 1);
  return (unsigned short)(u >> 16);
}
__device__ __forceinline__ float bf2f(unsigned short h) {
  return __uint_as_float(((unsigned)h) << 16);
}

// ---------------------------------------------------------------------------
// Prep 1: masked signed W packed into MFMA A-fragment layout, split hi/lo bf16.
// Afrag[(hg*13+c)] = 4 ksteps x {hi,lo} x 64 lanes x 8 bf16 (8 KB per chunk).
// A[m][k]: m = lane&15, k = (lane>>4)*8 + j   (m118-verified mapping).
// grid (160,13), block 256.
// ---------------------------------------------------------------------------
__global__ void build_wpack(const float* __restrict__ Wrec,
                            const float* __restrict__ Win,
                            unsigned short* __restrict__ Afrag) {
  int hg = blockIdx.x, c = blockIdx.y;
  int a = (hg < 128) ? (hg >> 5) : ((hg - 128) >> 3);
  int nE = (a == 0 || a == 3) ? 8 : 12;
  int nch = nE + 1 + (a == 0 ? 1 : 0);
  if (c >= nch) return;
  int h0 = hg * 16;
  int tid = threadIdx.x;
  int ks = tid >> 6, L = tid & 63;
  int m = L & 15, q = L >> 4;
  int h = h0 + m;

  const float* src; int k0, stride; float sgn; bool isIn = false;
  if (c < nE)       { k0 = ((a == 0 ? 0 : a - 1) << 9) + (c << 7); src = Wrec; stride = Hn;  sgn =  1.f; }
  else if (c == nE) { k0 = ETOT + (a << 7);                        src = Wrec; stride = Hn;  sgn = -1.f; }
  else              { k0 = 0;                                      src = Win;  stride = INW; sgn =  1.f; isIn = true; }

  unsigned short hi8[8], lo8[8];
  #pragma unroll
  for (int j = 0; j < 8; ++j) {
    int k = k0 + ks * 32 + q * 8 + j;
    float w = fabsf(src[(size_t)h * stride + k]);
    if (!isIn && k == h) w = 0.f;     // remove_diag
    w *= sgn;
    unsigned short hh = f2bf(w);
    hi8[j] = hh;
    lo8[j] = f2bf(w - bf2f(hh));
  }
  unsigned short* outp = Afrag + (size_t)(hg * MAXC + c) * 4096;
  *(uint4*)(outp + (ks * 2 + 0) * 512 + L * 8) = *(const uint4*)hi8;
  *(uint4*)(outp + (ks * 2 + 1) * 512 + L * 8) = *(const uint4*)lo8;
}

// ---------------------------------------------------------------------------
// Prep 2: fp32 masked Win in [k][16 m] layout (fallback VALU path only).
// 40 area-0 h-groups.
// ---------------------------------------------------------------------------
__global__ void build_winpack(const float* __restrict__ Win, float* __restrict__ WinPack) {
  int ia = blockIdx.x;
  int hg = ia < 32 ? ia : 128 + (ia - 32);
  int h0 = hg * 16;
  for (int idx = threadIdx.x; idx < 2048; idx += 256) {
    int k = idx >> 4, m = idx & 15;
    WinPack[(size_t)ia * 2048 + idx] = fabsf(Win[(size_t)(h0 + m) * INW + k]);
  }
}

// ---------------------------------------------------------------------------
// Prep 3: inputs[t] -> B-fragment hi/lo bf16 tiles. 32 KB per t.
// B[k][n]: n = lane&15, k = (lane>>4)*8 + j. Tiles [kt:4][bt:4][p:2][512 us].
// ---------------------------------------------------------------------------
__global__ void build_ifrag(const float* __restrict__ inp, unsigned short* __restrict__ F) {
  int t = blockIdx.x;
  const float* src = inp + (size_t)t * Bn * INW;
  unsigned short* dst = F + (size_t)t * 16384;
  for (int it = 0; it < 4; ++it) {
    int slot = threadIdx.x + it * 256;      // 1024 slots = 4 kt x 4 bt x 64 L
    int kt = slot >> 8, bt = (slot >> 6) & 3, L = slot & 63;
    int n  = bt * 16 + (L & 15);
    int i0 = kt * 32 + (L >> 4) * 8;
    unsigned short hi8[8], lo8[8];
    #pragma unroll
    for (int j = 0; j < 8; ++j) {
      float v = src[(size_t)n * INW + i0 + j];
      unsigned short hh = f2bf(v);
      hi8[j] = hh;
      lo8[j] = f2bf(v - bf2f(hh));
    }
    *(uint4*)(dst + ((kt * 4 + bt) * 2 + 0) * 512 + L * 8) = *(const uint4*)hi8;
    *(uint4*)(dst + ((kt * 4 + bt) * 2 + 1) * 512 + L * 8) = *(const uint4*)lo8;
  }
}

// ---------------------------------------------------------------------------
// Kernel A (per step): MFMA masked GEMM partials. 1800 single-wave blocks
// (R3/R6 chunk map). Per wave: 16h x 64b x 128k via 4 K-steps x 4 b-tiles x
// 3 split-precision mfma_f32_16x16x32_bf16. All operand loads are per-lane
// distributed 16 B (no broadcasts, no LDS in the hot path).
// ---------------------------------------------------------------------------
__global__ __launch_bounds__(64) void rnn_mm(
    const unsigned short* __restrict__ Afrag,
    const unsigned short* __restrict__ ifrag,
    const float* __restrict__ WinPack, const float* __restrict__ inp,
    const unsigned short* __restrict__ rfrag, float* __restrict__ part,
    int t, int useInpF)
{
  __shared__ float wlds[2048];       // fallback path only
  int bid = blockIdx.x;
  int L = threadIdx.x;

  // bid -> (h-group, chunk id)
  int hg, c;
  if (bid < 320)       { hg = bid / 10;                      c = bid - hg * 10;          }
  else if (bid < 1152) { int r = bid - 320;  hg = 32 + r / 13;  c = r - (hg - 32) * 13;  }
  else if (bid < 1440) { int r = bid - 1152; hg = 96 + r / 9;   c = r - (hg - 96) * 9;   }
  else if (bid < 1520) { int r = bid - 1440; hg = 128 + r / 10; c = r - (hg - 128) * 10; }
  else if (bid < 1728) { int r = bid - 1520; hg = 136 + r / 13; c = r - (hg - 136) * 13; }
  else                 { int r = bid - 1728; hg = 152 + r / 9;  c = r - (hg - 152) * 9;  }

  int a  = (hg < 128) ? (hg >> 5) : ((hg - 128) >> 3);
  int nE = (a == 0 || a == 3) ? 8 : 12;
  bool isIn = (c == nE + 1);
  float* pb = part + (size_t)(hg * MAXC + c) * 1024;

  if (isIn && !useInpF) {
    // fp32 VALU fallback for the input chunk (raw inputs, fp32 masked Win)
    int ia = hg < 32 ? hg : 32 + (hg - 128);
    const float* wsrc = WinPack + (size_t)ia * 2048;
    #pragma unroll
    for (int qq = 0; qq < 8; ++qq) ((float4*)wlds)[L + qq * 64] = ((const float4*)wsrc)[L + qq * 64];
    __syncthreads();
    const float* rp = inp + (size_t)t * Bn * INW;
    float acc[16];
    #pragma unroll
    for (int i = 0; i < 16; ++i) acc[i] = 0.f;
    #pragma unroll 4
    for (int k = 0; k < 128; ++k) {
      const float4* wq = (const float4*)(wlds + k * 16);
      float4 w0 = wq[0], w1 = wq[1], w2 = wq[2], w3 = wq[3];
      float rv = rp[L * INW + k];
      acc[ 0] = fmaf(w0.x, rv, acc[ 0]);  acc[ 1] = fmaf(w0.y, rv, acc[ 1]);
      acc[ 2] = fmaf(w0.z, rv, acc[ 2]);  acc[ 3] = fmaf(w0.w, rv, acc[ 3]);
      acc[ 4] = fmaf(w1.x, rv, acc[ 4]);  acc[ 5] = fmaf(w1.y, rv, acc[ 5]);
      acc[ 6] = fmaf(w1.z, rv, acc[ 6]);  acc[ 7] = fmaf(w1.w, rv, acc[ 7]);
      acc[ 8] = fmaf(w2.x, rv, acc[ 8]);  acc[ 9] = fmaf(w2.y, rv, acc[ 9]);
      acc[10] = fmaf(w2.z, rv, acc[10]);  acc[11] = fmaf(w2.w, rv, acc[11]);
      acc[12] = fmaf(w3.x, rv, acc[12]);  acc[13] = fmaf(w3.y, rv, acc[13]);
      acc[14] = fmaf(w3.z, rv, acc[14]);  acc[15] = fmaf(w3.w, rv, acc[15]);
    }
    #pragma unroll
    for (int h = 0; h < 16; ++h) pb[h * 64 + L] = acc[h];   // [m][n] layout
    return;
  }

  // ---- MFMA path ----
  int kt0;
  const unsigned short* Bf;
  if (isIn) { Bf = ifrag + (size_t)t * 16384; kt0 = 0; }
  else {
    int kE0 = (a == 0 ? 0 : (a - 1)) * 512;
    int k0  = (c < nE) ? (kE0 + (c << 7)) : (ETOT + (a << 7));
    Bf = rfrag; kt0 = k0 >> 5;
  }
  const unsigned short* Af = Afrag + (size_t)(hg * MAXC + c) * 4096;

  floatx4 ac0 = {0.f,0.f,0.f,0.f}, ac1 = {0.f,0.f,0.f,0.f};
  floatx4 ac2 = {0.f,0.f,0.f,0.f}, ac3 = {0.f,0.f,0.f,0.f};

  #pragma unroll
  for (int ks = 0; ks < 4; ++ks) {
    short8 ah = *(const short8*)(Af + (ks * 2 + 0) * 512 + L * 8);
    short8 al = *(const short8*)(Af + (ks * 2 + 1) * 512 + L * 8);
    const unsigned short* tb = Bf + (size_t)(kt0 + ks) * 4096;
    short8 b0h = *(const short8*)(tb + 0 * 1024 +   0 + L * 8);
    short8 b0l = *(const short8*)(tb + 0 * 1024 + 512 + L * 8);
    short8 b1h = *(const short8*)(tb + 1 * 1024 +   0 + L * 8);
    short8 b1l = *(const short8*)(tb + 1 * 1024 + 512 + L * 8);
    short8 b2h = *(const short8*)(tb + 2 * 1024 +   0 + L * 8);
    short8 b2l = *(const short8*)(tb + 2 * 1024 + 512 + L * 8);
    short8 b3h = *(const short8*)(tb + 3 * 1024 +   0 + L * 8);
    short8 b3l = *(const short8*)(tb + 3 * 1024 + 512 + L * 8);
    ac0 = __builtin_amdgcn_mfma_f32_16x16x32_bf16(ah, b0h, ac0, 0, 0, 0);
    ac0 = __builtin_amdgcn_mfma_f32_16x16x32_bf16(ah, b0l, ac0, 0, 0, 0);
    ac0 = __builtin_amdgcn_mfma_f32_16x16x32_bf16(al, b0h, ac0, 0, 0, 0);
    ac1 = __builtin_amdgcn_mfma_f32_16x16x32_bf16(ah, b1h, ac1, 0, 0, 0);
    ac1 = __builtin_amdgcn_mfma_f32_16x16x32_bf16(ah, b1l, ac1, 0, 0, 0);
    ac1 = __builtin_amdgcn_mfma_f32_16x16x32_bf16(al, b1h, ac1, 0, 0, 0);
    ac2 = __builtin_amdgcn_mfma_f32_16x16x32_bf16(ah, b2h, ac2, 0, 0, 0);
    ac2 = __builtin_amdgcn_mfma_f32_16x16x32_bf16(ah, b2l, ac2, 0, 0, 0);
    ac2 = __builtin_amdgcn_mfma_f32_16x16x32_bf16(al, b2h, ac2, 0, 0, 0);
    ac3 = __builtin_amdgcn_mfma_f32_16x16x32_bf16(ah, b3h, ac3, 0, 0, 0);
    ac3 = __builtin_amdgcn_mfma_f32_16x16x32_bf16(ah, b3l, ac3, 0, 0, 0);
    ac3 = __builtin_amdgcn_mfma_f32_16x16x32_bf16(al, b3h, ac3, 0, 0, 0);
  }

  // store partials in plain [m][n] layout: m = quad*4+p, n = bt*16 + (L&15)
  int q = L >> 4, n = L & 15;
  #pragma unroll
  for (int p = 0; p < 4; ++p) {
    int row = (q * 4 + p) * 64;
    pb[row +  0 + n] = ac0[p];
    pb[row + 16 + n] = ac1[p];
    pb[row + 32 + n] = ac2[p];
    pb[row + 48 + n] = ac3[p];
  }
}

// ---------------------------------------------------------------------------
// Kernel B (per step): reduce partials + bias + leaky-integrate + retanh;
// writes rates (fp32, packed) and next-step r in B-fragment hi/lo bf16.
// 160 blocks x 256 threads.
// ---------------------------------------------------------------------------
__global__ __launch_bounds__(256) void rnn_fin(
    const float* __restrict__ part, const float* __restrict__ brec,
    float* __restrict__ xT, unsigned short* __restrict__ rfragD,
    float* __restrict__ rates, int t)
{
  __shared__ float rrt[16][68];
  __shared__ unsigned short fr[2][4][32][8];   // [p][bt][lane_half][j]
  int hg = blockIdx.x;
  int a  = (hg < 128) ? (hg >> 5) : ((hg - 128) >> 3);
  int nE = (a == 0 || a == 3) ? 8 : 12;
  int nch = nE + 1 + (a == 0 ? 1 : 0);
  int h0 = hg * 16;
  int tid = threadIdx.x;
  int hh = tid >> 4, bq = tid & 15;            // (m, b-quad)

  const float4* p4 = (const float4*)(part + (size_t)hg * MAXC * 1024) + hh * 16 + bq;
  float4 s = make_float4(0.f, 0.f, 0.f, 0.f);
  for (int cc = 0; cc < nch; ++cc) {
    float4 v = p4[cc * 256];
    s.x += v.x; s.y += v.y; s.z += v.z; s.w += v.w;
  }
  float bb = brec[h0 + hh];
  float4* x4p = (float4*)xT + (size_t)(h0 + hh) * 16 + bq;
  float4 x = *x4p;
  x.x = 0.8f * x.x + 0.2f * (s.x + bb);        // ALPHA_X = 0.2
  x.y = 0.8f * x.y + 0.2f * (s.y + bb);
  x.z = 0.8f * x.z + 0.2f * (s.z + bb);
  x.w = 0.8f * x.w + 0.2f * (s.w + bb);
  *x4p = x;
  float r0 = tanhf(fmaxf(x.x, 0.f));
  float r1 = tanhf(fmaxf(x.y, 0.f));
  float r2 = tanhf(fmaxf(x.z, 0.f));
  float r3 = tanhf(fmaxf(x.w, 0.f));
  rrt[hh][bq * 4 + 0] = r0;
  rrt[hh][bq * 4 + 1] = r1;
  rrt[hh][bq * 4 + 2] = r2;
  rrt[hh][bq * 4 + 3] = r3;

  // B-fragment slots: unit u = h0+hh is a k-row; j = u&7, quad-in-half = hh>>3
  {
    int j = hh & 7, hq = hh >> 3;
    float rv[4] = {r0, r1, r2, r3};
    #pragma unroll
    for (int e = 0; e < 4; ++e) {
      int b = bq * 4 + e;
      int bt = b >> 4, lh = hq * 16 + (b & 15);
      unsigned short rh = f2bf(rv[e]);
      fr[0][bt][lh][j] = rh;
      fr[1][bt][lh][j] = f2bf(rv[e] - bf2f(rh));
    }
  }
  __syncthreads();

  // copy fragment halves out (coalesced 16 B per thread)
  {
    int p = tid >> 7, r7 = tid & 127, bt = r7 >> 5, lh = r7 & 31;
    int kt = hg >> 1;
    uint4 v = *(const uint4*)&fr[p][bt][lh][0];
    *(uint4*)(rfragD + (size_t)((kt * 4 + bt) * 2 + p) * 512 + (hg & 1) * 256 + lh * 8) = v;
  }

  // rates[t][b][h0..h0+15]: thread -> (b, h-quad), 64 B packed segments
  int b = tid >> 2, hq = tid & 3;
  float4 o = make_float4(rrt[hq * 4 + 0][b], rrt[hq * 4 + 1][b],
                         rrt[hq * 4 + 2][b], rrt[hq * 4 + 3][b]);
  *(float4*)(rates + (size_t)t * (Bn * Hn) + (size_t)b * Hn + h0 + hq * 4) = o;
}

// ---------------------------------------------------------------------------
extern "C" void kernel_launch(void* const* d_in, const int* in_sizes, int n_in,
                              void* d_out, int out_size, void* d_ws, size_t ws_size,
                              hipStream_t stream) {
  const float* inputs = (const float*)d_in[0];   // [T, 64, 128]
  const float* Wrec   = (const float*)d_in[1];   // [2560, 2560]
  const float* brec   = (const float*)d_in[2];   // [2560]
  const float* Win    = (const float*)d_in[3];   // [2560, 128]
  int T = in_sizes[0] / (Bn * INW);              // 500

  char* base = (char*)d_ws;
  size_t off = 0;
  unsigned short* Afrag = (unsigned short*)(base + off); off += (size_t)HGn * MAXC * 4096 * 2;  // 17.0 MB
  float* WinPack = (float*)(base + off); off += (size_t)40 * 2048 * 4;                          // 0.33 MB
  float* part    = (float*)(base + off); off += (size_t)HGn * MAXC * 1024 * 4;                  // 8.5 MB
  float* xT      = (float*)(base + off); off += (size_t)Hn * Bn * 4;                            // 0.64 MB
  unsigned short* rfA = (unsigned short*)(base + off); off += (size_t)80 * 4 * 2 * 512 * 2;     // 0.64 MB
  unsigned short* rfB = (unsigned short*)(base + off); off += (size_t)80 * 4 * 2 * 512 * 2;     // 0.64 MB
  unsigned short* ifrag = (unsigned short*)(base + off);
  size_t needI = off + (size_t)T * 16384 * 2;                                                   // +16 MB
  int useInpF = (ws_size >= needI) ? 1 : 0;

  // x0 = 0, r0 = retanh(0) = 0 (bf16 zero == 0x0000); ws poisoned each call
  hipMemsetAsync(xT,  0, (size_t)Hn * Bn * 4, stream);
  hipMemsetAsync(rfA, 0, (size_t)80 * 4 * 2 * 512 * 2, stream);

  build_wpack<<<dim3(HGn, MAXC), 256, 0, stream>>>(Wrec, Win, Afrag);
  build_winpack<<<40, 256, 0, stream>>>(Win, WinPack);
  if (useInpF) build_ifrag<<<T, 256, 0, stream>>>(inputs, ifrag);

  float* rates = (float*)d_out;
  for (int t = 0; t < T; ++t) {
    const unsigned short* rs = (t & 1) ? rfB : rfA;
    unsigned short*       rd = (t & 1) ? rfA : rfB;
    rnn_mm<<<1800, 64, 0, stream>>>(Afrag, ifrag, WinPack, inputs, rs, part, t, useInpF);
    rnn_fin<<<160, 256, 0, stream>>>(part, brec, xT, rd, rates, t);
  }
}

// Round 8
// 6245.670 us; speedup vs baseline: 4.2922x; 1.1979x over previous
//
#include <hip/hip_runtime.h>
#include <math.h>

// Problem constants (match reference)
#define Hn   2560      // hidden units
#define Bn   64        // batch
#define INW  128       // input width
#define ETOT 2048      // total excitatory units (4 areas x 512)
#define HGn  160       // h-groups of 16
#define MAXC 13        // max 128-k chunks per h-group

typedef __attribute__((ext_vector_type(8))) short short8;   // 8 bf16 = 4 VGPRs
typedef __attribute__((ext_vector_type(4))) float floatx4;  // MFMA acc

__device__ __forceinline__ unsigned short f2bf(float x) {   // RNE
  unsigned u = __float_as_uint(x);
  u += 0x7FFF + ((u >> 16) & 1);
  return (unsigned short)(u >> 16);
}
__device__ __forceinline__ float bf2f(unsigned short h) {
  return __uint_as_float(((unsigned)h) << 16);
}

// ---------------------------------------------------------------------------
// Prep 1: masked signed W packed into MFMA A-fragment layout, split hi/lo bf16.
// Afrag[(hg*13+c)] = 4 ksteps x {hi,lo} x 64 lanes x 8 bf16 (8 KB per chunk).
// A[m][k]: m = lane&15, k = (lane>>4)*8 + j.
// ---------------------------------------------------------------------------
__global__ void build_wpack(const float* __restrict__ Wrec,
                            const float* __restrict__ Win,
                            unsigned short* __restrict__ Afrag) {
  int hg = blockIdx.x, c = blockIdx.y;
  int a = (hg < 128) ? (hg >> 5) : ((hg - 128) >> 3);
  int nE = (a == 0 || a == 3) ? 8 : 12;
  int nch = nE + 1 + (a == 0 ? 1 : 0);
  if (c >= nch) return;
  int h0 = hg * 16;
  int tid = threadIdx.x;
  int ks = tid >> 6, L = tid & 63;
  int m = L & 15, q = L >> 4;
  int h = h0 + m;

  const float* src; int k0, stride; float sgn; bool isIn = false;
  if (c < nE)       { k0 = ((a == 0 ? 0 : a - 1) << 9) + (c << 7); src = Wrec; stride = Hn;  sgn =  1.f; }
  else if (c == nE) { k0 = ETOT + (a << 7);                        src = Wrec; stride = Hn;  sgn = -1.f; }
  else              { k0 = 0;                                      src = Win;  stride = INW; sgn =  1.f; isIn = true; }

  unsigned short hi8[8], lo8[8];
  #pragma unroll
  for (int j = 0; j < 8; ++j) {
    int k = k0 + ks * 32 + q * 8 + j;
    float w = fabsf(src[(size_t)h * stride + k]);
    if (!isIn && k == h) w = 0.f;     // remove_diag
    w *= sgn;
    unsigned short hh = f2bf(w);
    hi8[j] = hh;
    lo8[j] = f2bf(w - bf2f(hh));
  }
  unsigned short* outp = Afrag + (size_t)(hg * MAXC + c) * 4096;
  *(uint4*)(outp + (ks * 2 + 0) * 512 + L * 8) = *(const uint4*)hi8;
  *(uint4*)(outp + (ks * 2 + 1) * 512 + L * 8) = *(const uint4*)lo8;
}

// ---------------------------------------------------------------------------
// Prep 2: inputs[t] -> B-fragment hi/lo bf16 tiles (32 KB per t).
// B[k][n]: n = lane&15, k = (lane>>4)*8 + j. Tile (kt,bt) at (kt*4+bt)*1024.
// ---------------------------------------------------------------------------
__device__ __forceinline__ void ifrag_body(const float* src, unsigned short* dst, int tid) {
  for (int it = 0; it < 4; ++it) {
    int slot = tid + it * 256;              // 1024 slots = 4 kt x 4 bt x 64 L
    int kt = slot >> 8, bt = (slot >> 6) & 3, L = slot & 63;
    int n  = bt * 16 + (L & 15);
    int i0 = kt * 32 + (L >> 4) * 8;
    unsigned short hi8[8], lo8[8];
    #pragma unroll
    for (int j = 0; j < 8; ++j) {
      float v = src[(size_t)n * INW + i0 + j];
      unsigned short hh = f2bf(v);
      hi8[j] = hh;
      lo8[j] = f2bf(v - bf2f(hh));
    }
    *(uint4*)(dst + ((kt * 4 + bt) * 2 + 0) * 512 + L * 8) = *(const uint4*)hi8;
    *(uint4*)(dst + ((kt * 4 + bt) * 2 + 1) * 512 + L * 8) = *(const uint4*)lo8;
  }
}

__global__ void build_ifrag(const float* __restrict__ inp, unsigned short* __restrict__ F) {
  int t = blockIdx.x;
  ifrag_body(inp + (size_t)t * Bn * INW, F + (size_t)t * 16384, threadIdx.x);
}

__global__ void build_ifrag_one(const float* __restrict__ inp, unsigned short* __restrict__ F, int t) {
  ifrag_body(inp + (size_t)t * Bn * INW, F, threadIdx.x);
}

// ---------------------------------------------------------------------------
// Fused per-step kernel: ONE dispatch per step. 160 blocks x 256 thr.
// Block = one 16-h group; wave w = b-tile w (16 batches), accumulates the
// FULL masked K in a single 16x16 MFMA accumulator (no split-k, no partials).
// A-chunks (8 KB) double-buffered through LDS so the 17 MB A-stream is read
// exactly once per step; B fragments per-lane distributed from global
// (rfrag 0.64 MB, L2-resident). Epilogue fully in-block.
// ---------------------------------------------------------------------------
__global__ __launch_bounds__(256) void rnn_step(
    const unsigned short* __restrict__ Afrag,
    const unsigned short* __restrict__ ifr,   // this step's input B-fragments
    const unsigned short* __restrict__ rf,    // prev r B-fragments (all 2560 k)
    unsigned short* __restrict__ rfD,         // next r B-fragments
    const float* __restrict__ brec,
    float* __restrict__ xT, float* __restrict__ rates)
{
  __shared__ short Abuf[2][4096];            // 2 x 8 KB A double-buffer
  __shared__ float rrt[16][68];
  __shared__ unsigned short fr[2][4][32][8];

  int hg  = blockIdx.x;
  int tid = threadIdx.x;
  int w   = tid >> 6;        // wave = b-tile 0..3
  int L   = tid & 63;
  int h0  = hg * 16;
  int a   = (hg < 128) ? (hg >> 5) : ((hg - 128) >> 3);
  int nE  = (a == 0 || a == 3) ? 8 : 12;
  int nch = nE + 1 + (a == 0 ? 1 : 0);       // 10 / 13 / 13 / 9
  int ktE0 = (a == 0 ? 0 : (a - 1)) * 16;    // E base in 32-k tiles
  int ktI0 = 64 + a * 4;                     // I base in 32-k tiles

  const uint4* asrc = (const uint4*)(Afrag + (size_t)hg * MAXC * 4096);

  // prefetch chunk 0 into buffer 0
  uint4 pf0 = asrc[tid], pf1 = asrc[tid + 256];
  ((uint4*)Abuf[0])[tid] = pf0;
  ((uint4*)Abuf[0])[tid + 256] = pf1;
  __syncthreads();

  floatx4 ac = {0.f, 0.f, 0.f, 0.f};

  for (int c = 0; c < nch; ++c) {
    if (c + 1 < nch) {                       // issue next A-chunk global loads
      const uint4* s = asrc + (size_t)(c + 1) * 512;
      pf0 = s[tid]; pf1 = s[tid + 256];
    }

    // B source + kt base for this chunk
    const unsigned short* Bf;
    int kt0;
    if (c < nE)       { Bf = rf;  kt0 = ktE0 + c * 4; }
    else if (c == nE) { Bf = rf;  kt0 = ktI0; }
    else              { Bf = ifr; kt0 = 0; }

    const short* Ab = Abuf[c & 1];
    #pragma unroll
    for (int ks = 0; ks < 4; ++ks) {
      short8 ah = *(const short8*)(Ab + (ks * 2 + 0) * 512 + L * 8);
      short8 al = *(const short8*)(Ab + (ks * 2 + 1) * 512 + L * 8);
      const unsigned short* tb = Bf + (size_t)(kt0 + ks) * 4096 + w * 1024;
      short8 bh = *(const short8*)(tb +   0 + L * 8);
      short8 bl = *(const short8*)(tb + 512 + L * 8);
      ac = __builtin_amdgcn_mfma_f32_16x16x32_bf16(ah, bh, ac, 0, 0, 0);
      ac = __builtin_amdgcn_mfma_f32_16x16x32_bf16(ah, bl, ac, 0, 0, 0);
      ac = __builtin_amdgcn_mfma_f32_16x16x32_bf16(al, bh, ac, 0, 0, 0);
    }

    if (c + 1 < nch) {                       // write prefetched chunk to LDS
      ((uint4*)Abuf[(c + 1) & 1])[tid] = pf0;
      ((uint4*)Abuf[(c + 1) & 1])[tid + 256] = pf1;
    }
    __syncthreads();
  }

  // ---- epilogue (wave-local acc is the complete sum) ----
  int q = L >> 4, nh = L & 15;
  int n = w * 16 + nh;                       // batch index
  #pragma unroll
  for (int p = 0; p < 4; ++p) {
    int m = q * 4 + p;
    size_t idx = (size_t)(h0 + m) * 64 + n;
    float pre = ac[p] + brec[h0 + m];
    float x = xT[idx];
    x = 0.8f * x + 0.2f * pre;               // ALPHA_X = 0.2
    xT[idx] = x;
    rrt[m][n] = tanhf(fmaxf(x, 0.f));
  }
  __syncthreads();

  // next-step r B-fragments (hi/lo) staged in LDS then written coalesced
  {
    int hh = tid >> 4, bq = tid & 15;
    int j = hh & 7, hq3 = hh >> 3;
    #pragma unroll
    for (int e = 0; e < 4; ++e) {
      int b = bq * 4 + e;
      int bt = b >> 4, lh = hq3 * 16 + (b & 15);
      float rv = rrt[hh][b];
      unsigned short rh = f2bf(rv);
      fr[0][bt][lh][j] = rh;
      fr[1][bt][lh][j] = f2bf(rv - bf2f(rh));
    }
  }
  __syncthreads();
  {
    int p = tid >> 7, r7 = tid & 127, bt = r7 >> 5, lh = r7 & 31;
    int kt = hg >> 1;
    uint4 v = *(const uint4*)&fr[p][bt][lh][0];
    *(uint4*)(rfD + (size_t)((kt * 4 + bt) * 2 + p) * 512 + (hg & 1) * 256 + lh * 8) = v;
  }

  // rates[t][b][h0..h0+15]: thread -> (b, h-quad), 64 B packed segments
  {
    int b = tid >> 2, hq = tid & 3;
    float4 o = make_float4(rrt[hq * 4 + 0][b], rrt[hq * 4 + 1][b],
                           rrt[hq * 4 + 2][b], rrt[hq * 4 + 3][b]);
    *(float4*)(rates + (size_t)b * Hn + h0 + hq * 4) = o;
  }
}

// ---------------------------------------------------------------------------
extern "C" void kernel_launch(void* const* d_in, const int* in_sizes, int n_in,
                              void* d_out, int out_size, void* d_ws, size_t ws_size,
                              hipStream_t stream) {
  const float* inputs = (const float*)d_in[0];   // [T, 64, 128]
  const float* Wrec   = (const float*)d_in[1];   // [2560, 2560]
  const float* brec   = (const float*)d_in[2];   // [2560]
  const float* Win    = (const float*)d_in[3];   // [2560, 128]
  int T = in_sizes[0] / (Bn * INW);              // 500

  char* base = (char*)d_ws;
  size_t off = 0;
  unsigned short* Afrag = (unsigned short*)(base + off); off += (size_t)HGn * MAXC * 4096 * 2;  // 17.0 MB
  float* xT = (float*)(base + off); off += (size_t)Hn * Bn * 4;                                 // 0.64 MB
  unsigned short* rfA = (unsigned short*)(base + off); off += (size_t)80 * 4 * 2 * 512 * 2;     // 0.64 MB
  unsigned short* rfB = (unsigned short*)(base + off); off += (size_t)80 * 4 * 2 * 512 * 2;     // 0.64 MB
  unsigned short* ifr1 = (unsigned short*)(base + off); off += 16384 * 2;                       // 32 KB
  unsigned short* ifrag = (unsigned short*)(base + off);
  size_t needI = off + (size_t)T * 16384 * 2;                                                   // +16 MB
  int useInpF = (ws_size >= needI) ? 1 : 0;

  // x0 = 0, r0 = retanh(0) = 0 (bf16 zero == 0x0000); ws poisoned each call
  hipMemsetAsync(xT,  0, (size_t)Hn * Bn * 4, stream);
  hipMemsetAsync(rfA, 0, (size_t)80 * 4 * 2 * 512 * 2, stream);

  build_wpack<<<dim3(HGn, MAXC), 256, 0, stream>>>(Wrec, Win, Afrag);
  if (useInpF) build_ifrag<<<T, 256, 0, stream>>>(inputs, ifrag);

  float* rates = (float*)d_out;
  for (int t = 0; t < T; ++t) {
    const unsigned short* rs = (t & 1) ? rfB : rfA;
    unsigned short*       rd = (t & 1) ? rfA : rfB;
    const unsigned short* ip;
    if (useInpF) ip = ifrag + (size_t)t * 16384;
    else { build_ifrag_one<<<1, 256, 0, stream>>>(inputs, ifr1, t); ip = ifr1; }
    rnn_step<<<HGn, 256, 0, stream>>>(Afrag, ip, rs, rd, brec, xT,
                                      rates + (size_t)t * (Bn * Hn));
  }
}